// Round 1
// baseline (1003.992 us; speedup 1.0000x reference)
//
#include <hip/hip_runtime.h>
#include <stdint.h>

typedef __bf16 bf16x8 __attribute__((ext_vector_type(8)));
typedef float  f32x4  __attribute__((ext_vector_type(4)));

#define MFMA16(a, b, c) __builtin_amdgcn_mfma_f32_16x16x32_bf16((a), (b), (c), 0, 0, 0)

static constexpr int   kBz = 64, kNn = 577, kEe = 768, kHh = 8, kDd = 96;
static constexpr int   kM  = kBz * kNn;  // 36928 tokens
static constexpr float kScale = 0.10206207261596575f;  // 96^-0.5

__device__ __forceinline__ unsigned short f2bf(float f) {
  unsigned u = __float_as_uint(f);
  u += 0x7fffu + ((u >> 16) & 1u);  // RNE
  return (unsigned short)(u >> 16);
}
__device__ __forceinline__ float bf2f(unsigned short s) {
  return __uint_as_float(((unsigned)s) << 16);
}

__device__ __forceinline__ void gload16(const void* g, void* l) {
  __builtin_amdgcn_global_load_lds(
      (const __attribute__((address_space(1))) void*)(void*)g,
      (__attribute__((address_space(3))) void*)l, 16, 0, 0);
}

// ---------------- kernel 1: split x into bf16 hi/lo ----------------
__global__ __launch_bounds__(256) void k_castx(const float* __restrict__ x,
                                               unsigned short* __restrict__ xh,
                                               unsigned short* __restrict__ xl) {
  const int i = blockIdx.x * 256 + threadIdx.x;
  if (i >= kM * kEe / 4) return;
  const float4 v = reinterpret_cast<const float4*>(x)[i];
  float f[4] = {v.x, v.y, v.z, v.w};
  ushort4 h, lo;
  unsigned short hs[4], ls[4];
#pragma unroll
  for (int j = 0; j < 4; ++j) {
    hs[j] = f2bf(f[j]);
    ls[j] = f2bf(f[j] - bf2f(hs[j]));
  }
  h.x = hs[0]; h.y = hs[1]; h.z = hs[2]; h.w = hs[3];
  lo.x = ls[0]; lo.y = ls[1]; lo.z = ls[2]; lo.w = ls[3];
  reinterpret_cast<ushort4*>(xh)[i] = h;
  reinterpret_cast<ushort4*>(xl)[i] = lo;
}

// ------- kernel 2: build W^T concat [3*768 n][2304 k] = [hi | lo | hi] -------
__global__ __launch_bounds__(256) void k_wcat(const float* __restrict__ Wq,
                                              const float* __restrict__ Wk,
                                              const float* __restrict__ Wv,
                                              unsigned short* __restrict__ wcat) {
  const int o = blockIdx.x * 256 + threadIdx.x;
  if (o >= 3 * 768 * 2304) return;
  const int gn = o / 2304, ks = o - gn * 2304;
  const int seg = ks / 768, k = ks - seg * 768;
  const int mat = gn / 768, n = gn - mat * 768;
  const float* W = (mat == 0) ? Wq : ((mat == 1) ? Wk : Wv);
  const float v = W[k * 768 + n];  // W is [k][n] row-major
  const unsigned short h = f2bf(v);
  wcat[o] = (seg == 1) ? f2bf(v - bf2f(h)) : h;
}

// ------- kernel 3: QKV projection GEMM (M=36928, N=2304, K=2304 split) -------
__global__ __launch_bounds__(256) void k_proj(
    const unsigned short* __restrict__ xh, const unsigned short* __restrict__ xl,
    const unsigned short* __restrict__ wcat,
    const float* __restrict__ bq, const float* __restrict__ bk, const float* __restrict__ bv,
    unsigned short* __restrict__ Qh, unsigned short* __restrict__ Ql,
    unsigned short* __restrict__ Kh, unsigned short* __restrict__ Kl,
    unsigned short* __restrict__ V) {
  __shared__ __align__(16) char sA[16384];  // [128 rows][64 bf16 = 128B], xor-swizzled
  __shared__ __align__(16) char sB[16384];  // [128 n-rows][64 bf16]
  const int ntile = blockIdx.x, mtile = blockIdx.y;
  const int tid = threadIdx.x, w = tid >> 6, l = tid & 63;
  const int wm = w >> 1, wn = w & 1;

  f32x4 acc[4][4];
  const f32x4 fz = {0.f, 0.f, 0.f, 0.f};
#pragma unroll
  for (int i = 0; i < 4; ++i)
#pragma unroll
    for (int j = 0; j < 4; ++j) acc[i][j] = fz;

  const int lrow8 = l >> 3;            // row-within-instr 0..7
  const int lc_sw = (l & 7) ^ lrow8;   // pre-swizzled logical col16

  for (int kt = 0; kt < 36; ++kt) {
    const unsigned short* Asrc = (kt < 24) ? xh : xl;
    const int kx = (kt % 12) * 64;
#pragma unroll
    for (int i = 0; i < 4; ++i) {
      const int g = w * 4 + i;  // staging instr 0..15, 8 rows each
      int m = mtile * 128 + 8 * g + lrow8;
      if (m > kM - 1) m = kM - 1;
      gload16(Asrc + (size_t)m * kEe + kx + lc_sw * 8, sA + g * 1024);
      const int bn = ntile * 128 + 8 * g + lrow8;
      gload16(wcat + (size_t)bn * 2304 + kt * 64 + lc_sw * 8, sB + g * 1024);
    }
    __syncthreads();
#pragma unroll
    for (int ks = 0; ks < 2; ++ks) {
      bf16x8 av[4], bv_[4];
#pragma unroll
      for (int mi = 0; mi < 4; ++mi) {
        const int row = wm * 64 + mi * 16 + (l & 15);
        const int c16 = ((ks * 4) + (l >> 4)) ^ (row & 7);
        av[mi] = *reinterpret_cast<const bf16x8*>(sA + row * 128 + c16 * 16);
      }
#pragma unroll
      for (int ni = 0; ni < 4; ++ni) {
        const int row = wn * 64 + ni * 16 + (l & 15);
        const int c16 = ((ks * 4) + (l >> 4)) ^ (row & 7);
        bv_[ni] = *reinterpret_cast<const bf16x8*>(sB + row * 128 + c16 * 16);
      }
#pragma unroll
      for (int mi = 0; mi < 4; ++mi)
#pragma unroll
        for (int ni = 0; ni < 4; ++ni)
          acc[mi][ni] = MFMA16(av[mi], bv_[ni], acc[mi][ni]);
    }
    __syncthreads();
  }

  // epilogue: bias add, split to bf16 hi/lo, write [B,H,N,D]
  const int matrix = ntile / 6;  // 0=Q 1=K 2=V
  const float* bias = (matrix == 0) ? bq : ((matrix == 1) ? bk : bv);
  int hh[4], dd[4];
  float bb[4];
#pragma unroll
  for (int ni = 0; ni < 4; ++ni) {
    const int gn = ntile * 128 + wn * 64 + ni * 16 + (l & 15);
    const int n_in = gn - matrix * 768;
    hh[ni] = n_in / 96;
    dd[ni] = n_in - hh[ni] * 96;
    bb[ni] = bias[n_in];
  }
#pragma unroll
  for (int mi = 0; mi < 4; ++mi) {
#pragma unroll
    for (int r = 0; r < 4; ++r) {
      const int m = mtile * 128 + wm * 64 + mi * 16 + (l >> 4) * 4 + r;
      if (m >= kM) continue;
      const int bidx = m / 577;
      const int n = m - bidx * 577;
#pragma unroll
      for (int ni = 0; ni < 4; ++ni) {
        const float val = acc[mi][ni][r] + bb[ni];
        const size_t o = ((size_t)(bidx * 8 + hh[ni]) * 577 + n) * 96 + dd[ni];
        if (matrix == 0) {
          const unsigned short hi = f2bf(val);
          Qh[o] = hi; Ql[o] = f2bf(val - bf2f(hi));
        } else if (matrix == 1) {
          const unsigned short hi = f2bf(val);
          Kh[o] = hi; Kl[o] = f2bf(val - bf2f(hi));
        } else {
          V[o] = f2bf(val);
        }
      }
    }
  }
}

// ---------------- kernel 4: V [bh][577][96] -> V^T [bh][96][640] ----------------
__global__ __launch_bounds__(256) void k_vt(const unsigned short* __restrict__ V,
                                            unsigned short* __restrict__ Vt) {
  __shared__ unsigned int Tu[32][49];
  const int nt = blockIdx.x, bh = blockIdx.y;
  const int t = threadIdx.x;
  const unsigned int* Vu = reinterpret_cast<const unsigned int*>(V);
  unsigned int* Vtu = reinterpret_cast<unsigned int*>(Vt);
  const int n0 = nt * 32;
#pragma unroll
  for (int i = 0; i < 6; ++i) {
    const int u = t + i * 256;  // < 1536
    const int ln = u / 48, cu = u - ln * 48;
    int n = n0 + ln; if (n > 576) n = 576;
    Tu[ln][cu] = Vu[(size_t)(bh * 577 + n) * 48 + cu];
  }
  __syncthreads();
#pragma unroll
  for (int i = 0; i < 6; ++i) {
    const int u = t + i * 256;
    const int d = u / 16, cu = u - d * 16;
    const unsigned int w0 = Tu[2 * cu][d >> 1];
    const unsigned int w1 = Tu[2 * cu + 1][d >> 1];
    const int sh = (d & 1) * 16;
    Vtu[(size_t)(bh * 96 + d) * 320 + nt * 16 + cu] =
        ((w0 >> sh) & 0xffffu) | (((w1 >> sh) & 0xffffu) << 16);
  }
}

// ---------------- kernel 5: fused flash attention ----------------
__global__ __launch_bounds__(256) void k_attn(
    const unsigned short* __restrict__ Qh, const unsigned short* __restrict__ Ql,
    const unsigned short* __restrict__ Kh, const unsigned short* __restrict__ Kl,
    const unsigned short* __restrict__ Vt, float* __restrict__ out) {
  __shared__ __align__(16) char sKH[16384];   // [64 kv][128 bf16 rows=256B], swizzled
  __shared__ __align__(16) char sKL[16384];
  __shared__ __align__(16) char sVT[12288];   // [96 d][64 bf16 = 128B], swizzled
  __shared__ __align__(16) char sP[4][2304];  // per-wave P: [16 q][72 bf16 = 144B]
  const int qt = blockIdx.x, bh = blockIdx.y;
  const int tid = threadIdx.x, w = tid >> 6, l = tid & 63;
  const int bb_ = bh >> 3, hh_ = bh & 7;
  const size_t hdbase = (size_t)bh * 577 * 96;

  const int qrow = qt * 64 + w * 16 + (l & 15);
  const int qn = (qrow > 576) ? 576 : qrow;

  // Q hoisted to registers: B-operand frags (hi/lo) for 3 d-ksteps
  bf16x8 fqh[3], fql[3];
#pragma unroll
  for (int ks = 0; ks < 3; ++ks) {
    const size_t off = hdbase + (size_t)qn * 96 + ks * 32 + (l >> 4) * 8;
    fqh[ks] = *reinterpret_cast<const bf16x8*>(Qh + off);
    fql[ks] = *reinterpret_cast<const bf16x8*>(Ql + off);
  }

  f32x4 accO[6];
  const f32x4 fz = {0.f, 0.f, 0.f, 0.f};
#pragma unroll
  for (int i = 0; i < 6; ++i) accO[i] = fz;
  float mrun = -1e30f, lrun = 0.f;

  for (int kt = 0; kt < 10; ++kt) {
    // ---- stage K hi/lo + V^T tiles (44 x 1KB gload_lds, 11 per wave) ----
#pragma unroll
    for (int i = 0; i < 11; ++i) {
      const int j = w * 11 + i;
      if (j < 32) {
        const int jj = j & 15;
        const int r = 4 * jj + (l >> 4);
        const int lc = (l & 15) ^ (r & 7);
        const int lc2 = (lc < 12) ? lc : 11;
        int kvn = kt * 64 + r; if (kvn > 576) kvn = 576;
        const unsigned short* src = (j < 16) ? Kh : Kl;
        char* dst = (j < 16) ? (sKH + jj * 1024) : (sKL + jj * 1024);
        gload16(src + hdbase + (size_t)kvn * 96 + lc2 * 8, dst);
      } else {
        const int j2 = j - 32;
        const int d = 8 * j2 + (l >> 3);
        const int lc = (l & 7) ^ (d & 7);
        gload16(Vt + (size_t)(bh * 96 + d) * 640 + kt * 64 + lc * 8, sVT + j2 * 1024);
      }
    }
    __syncthreads();

    // ---- S^T = K · Q^T, 3-term bf16x2 split ----
    f32x4 s_[4];
#pragma unroll
    for (int i = 0; i < 4; ++i) s_[i] = fz;
#pragma unroll
    for (int ks = 0; ks < 3; ++ks) {
#pragma unroll
      for (int af = 0; af < 4; ++af) {
        const int r = af * 16 + (l & 15);
        const int c16 = ((ks * 4) + (l >> 4)) ^ (r & 7);
        const bf16x8 kh = *reinterpret_cast<const bf16x8*>(sKH + r * 256 + c16 * 16);
        const bf16x8 kl = *reinterpret_cast<const bf16x8*>(sKL + r * 256 + c16 * 16);
        s_[af] = MFMA16(kh, fqh[ks], s_[af]);
        s_[af] = MFMA16(kh, fql[ks], s_[af]);
        s_[af] = MFMA16(kl, fqh[ks], s_[af]);
      }
    }

    if (kt == 9) {  // mask kv >= 577
#pragma unroll
      for (int af = 0; af < 4; ++af) {
        const int kv0 = 576 + af * 16 + (l >> 4) * 4;
#pragma unroll
        for (int r = 0; r < 4; ++r)
          if (kv0 + r >= 577) s_[af][r] = -1e30f;
      }
    }

    // ---- online softmax (lane holds 16 kv of its q-row; reduce over 4 lanes) ----
    float pmax = -1e30f;
#pragma unroll
    for (int af = 0; af < 4; ++af)
#pragma unroll
      for (int r = 0; r < 4; ++r) pmax = fmaxf(pmax, s_[af][r]);
    pmax = fmaxf(pmax, __shfl_xor(pmax, 16, 64));
    pmax = fmaxf(pmax, __shfl_xor(pmax, 32, 64));
    const float mnew = fmaxf(mrun, pmax);
    const float fsc = __expf(mrun - mnew);
    float psum = 0.f;
    char* pbase = sP[w] + (l & 15) * 144;
#pragma unroll
    for (int af = 0; af < 4; ++af) {
      const float p0 = __expf(s_[af][0] - mnew);
      const float p1 = __expf(s_[af][1] - mnew);
      const float p2 = __expf(s_[af][2] - mnew);
      const float p3 = __expf(s_[af][3] - mnew);
      psum += (p0 + p1) + (p2 + p3);
      const unsigned w0 = (unsigned)f2bf(p0) | ((unsigned)f2bf(p1) << 16);
      const unsigned w1 = (unsigned)f2bf(p2) | ((unsigned)f2bf(p3) << 16);
      *reinterpret_cast<unsigned*>(pbase + af * 32 + (l >> 4) * 8) = w0;
      *reinterpret_cast<unsigned*>(pbase + af * 32 + (l >> 4) * 8 + 4) = w1;
    }
    psum += __shfl_xor(psum, 16, 64);
    psum += __shfl_xor(psum, 32, 64);
    lrun = lrun * fsc + psum;
    mrun = mnew;
#pragma unroll
    for (int i = 0; i < 6; ++i)
#pragma unroll
      for (int r = 0; r < 4; ++r) accO[i][r] *= fsc;
    __syncthreads();  // cross-lane P visibility

    // ---- O^T += V^T · P^T ----
#pragma unroll
    for (int ks = 0; ks < 2; ++ks) {
      const bf16x8 pb = *reinterpret_cast<const bf16x8*>(
          sP[w] + (l & 15) * 144 + ks * 64 + (l >> 4) * 16);
#pragma unroll
      for (int df = 0; df < 6; ++df) {
        const int r = df * 16 + (l & 15);
        const int c16 = ((ks * 4) + (l >> 4)) ^ (r & 7);
        const bf16x8 va = *reinterpret_cast<const bf16x8*>(sVT + r * 128 + c16 * 16);
        accO[df] = MFMA16(va, pb, accO[df]);
      }
    }
    __syncthreads();  // reads done before next stage overwrites
  }

  // ---- epilogue: out[b][n][h*96+d] = O * scale / l ----
  if (qrow <= 576) {
    const float inv = kScale / lrun;
#pragma unroll
    for (int df = 0; df < 6; ++df) {
      float4 o;
      o.x = accO[df][0] * inv; o.y = accO[df][1] * inv;
      o.z = accO[df][2] * inv; o.w = accO[df][3] * inv;
      const size_t oo = ((size_t)bb_ * 577 + qrow) * 768 + hh_ * 96 + df * 16 + (l >> 4) * 4;
      *reinterpret_cast<float4*>(out + oo) = o;
    }
  }
}

extern "C" void kernel_launch(void* const* d_in, const int* in_sizes, int n_in,
                              void* d_out, int out_size, void* d_ws, size_t ws_size,
                              hipStream_t stream) {
  const float* x  = (const float*)d_in[0];
  const float* Wq = (const float*)d_in[1];
  const float* bq = (const float*)d_in[2];
  const float* Wk = (const float*)d_in[3];
  const float* bk = (const float*)d_in[4];
  const float* Wv = (const float*)d_in[5];
  const float* bv = (const float*)d_in[6];
  float* out = (float*)d_out;
  char* ws = (char*)d_ws;

  const size_t SZ = 56721408;  // 36928*768*2 == 512*577*96*2 bytes
  unsigned short* xh   = (unsigned short*)(ws);
  unsigned short* xl   = (unsigned short*)(ws + SZ);
  unsigned short* wcat = (unsigned short*)(ws + 2 * SZ);
  unsigned short* Qh   = (unsigned short*)(ws + 2 * SZ + 10616832);
  unsigned short* Ql   = (unsigned short*)(ws + 3 * SZ + 10616832);
  unsigned short* Kh   = (unsigned short*)(ws + 4 * SZ + 10616832);
  unsigned short* Kl   = (unsigned short*)(ws + 5 * SZ + 10616832);
  unsigned short* V    = (unsigned short*)(ws + 6 * SZ + 10616832);
  unsigned short* Vt   = (unsigned short*)(ws);  // aliases xh/xl (dead after k_proj)

  k_castx<<<27696, 256, 0, stream>>>(x, xh, xl);
  k_wcat<<<20736, 256, 0, stream>>>(Wq, Wk, Wv, wcat);
  k_proj<<<dim3(18, 289), 256, 0, stream>>>(xh, xl, wcat, bq, bk, bv, Qh, Ql, Kh, Kl, V);
  k_vt<<<dim3(20, 512), 256, 0, stream>>>(V, Vt);
  k_attn<<<dim3(10, 512), 256, 0, stream>>>(Qh, Ql, Kh, Kl, Vt, out);
}

// Round 2
// 877.803 us; speedup vs baseline: 1.1438x; 1.1438x over previous
//
#include <hip/hip_runtime.h>
#include <stdint.h>

typedef __bf16 bf16x8 __attribute__((ext_vector_type(8)));
typedef float  f32x4  __attribute__((ext_vector_type(4)));

#define MFMA16(a, b, c) __builtin_amdgcn_mfma_f32_16x16x32_bf16((a), (b), (c), 0, 0, 0)

static constexpr int   kBz = 64, kNn = 577, kEe = 768, kHh = 8, kDd = 96;
static constexpr int   kM  = kBz * kNn;  // 36928 tokens
static constexpr float kScale = 0.10206207261596575f;  // 96^-0.5

__device__ __forceinline__ unsigned short f2bf(float f) {
  unsigned u = __float_as_uint(f);
  u += 0x7fffu + ((u >> 16) & 1u);  // RNE
  return (unsigned short)(u >> 16);
}
__device__ __forceinline__ float bf2f(unsigned short s) {
  return __uint_as_float(((unsigned)s) << 16);
}

__device__ __forceinline__ void gload16(const void* g, void* l) {
  __builtin_amdgcn_global_load_lds(
      (const __attribute__((address_space(1))) void*)(void*)g,
      (__attribute__((address_space(3))) void*)l, 16, 0, 0);
}

// ---------------- kernel 1: split x into bf16 hi/lo ----------------
__global__ __launch_bounds__(256) void k_castx(const float* __restrict__ x,
                                               unsigned short* __restrict__ xh,
                                               unsigned short* __restrict__ xl) {
  const int i = blockIdx.x * 256 + threadIdx.x;
  if (i >= kM * kEe / 4) return;
  const float4 v = reinterpret_cast<const float4*>(x)[i];
  float f[4] = {v.x, v.y, v.z, v.w};
  ushort4 h, lo;
  unsigned short hs[4], ls[4];
#pragma unroll
  for (int j = 0; j < 4; ++j) {
    hs[j] = f2bf(f[j]);
    ls[j] = f2bf(f[j] - bf2f(hs[j]));
  }
  h.x = hs[0]; h.y = hs[1]; h.z = hs[2]; h.w = hs[3];
  lo.x = ls[0]; lo.y = ls[1]; lo.z = ls[2]; lo.w = ls[3];
  reinterpret_cast<ushort4*>(xh)[i] = h;
  reinterpret_cast<ushort4*>(xl)[i] = lo;
}

// ------- kernel 2: build W^T concat [3*768 n][2304 k] = [hi | lo | hi] -------
__global__ __launch_bounds__(256) void k_wcat(const float* __restrict__ Wq,
                                              const float* __restrict__ Wk,
                                              const float* __restrict__ Wv,
                                              unsigned short* __restrict__ wcat) {
  const int o = blockIdx.x * 256 + threadIdx.x;
  if (o >= 3 * 768 * 2304) return;
  const int gn = o / 2304, ks = o - gn * 2304;
  const int seg = ks / 768, k = ks - seg * 768;
  const int mat = gn / 768, n = gn - mat * 768;
  const float* W = (mat == 0) ? Wq : ((mat == 1) ? Wk : Wv);
  const float v = W[k * 768 + n];  // W is [k][n] row-major
  const unsigned short h = f2bf(v);
  wcat[o] = (seg == 1) ? f2bf(v - bf2f(h)) : h;
}

// ------- kernel 3: QKV projection GEMM, 256x256x64 8-phase schedule -------
// A = [xh | xh | xl] (M=36928, K=2304), B = wcat^T rows (N=2304, K=2304).
// 8 waves (2M x 4N), per-wave 128x64 output. LDS: A[2][256][64] + B[2][256][64]
// bf16, XOR-swizzled (16B slot ^= row&7). Counted vmcnt(4) once per K-tile.
struct ProjArgs {
  const unsigned short* xh; const unsigned short* xl; const unsigned short* wcat;
};

__device__ __forceinline__ void stageA(const ProjArgs& pa, int kt, char* Abuf, int g,
                                       int mtile, int lrow8, int lc_sw) {
  const unsigned short* src = (kt < 24) ? pa.xh : pa.xl;
  const int kx = (kt % 12) * 64;
  int m = mtile * 256 + 8 * g + lrow8;
  if (m > kM - 1) m = kM - 1;
  gload16(src + (size_t)m * 768 + kx + lc_sw * 8, Abuf + g * 1024);
}
__device__ __forceinline__ void stageB(const ProjArgs& pa, int kt, char* Bbuf, int g,
                                       int ntile, int lrow8, int lc_sw) {
  const int bn = ntile * 256 + 8 * g + lrow8;
  gload16(pa.wcat + (size_t)bn * 2304 + kt * 64 + lc_sw * 8, Bbuf + g * 1024);
}

__global__ __launch_bounds__(512, 2) void k_proj(
    const unsigned short* __restrict__ xh, const unsigned short* __restrict__ xl,
    const unsigned short* __restrict__ wcat,
    const float* __restrict__ bq, const float* __restrict__ bk, const float* __restrict__ bv,
    unsigned short* __restrict__ Qh, unsigned short* __restrict__ Ql,
    unsigned short* __restrict__ Kh, unsigned short* __restrict__ Kl,
    unsigned short* __restrict__ V) {
  extern __shared__ char smem[];  // 131072 B: A[2] @0/32768, B[2] @65536/98304
  const ProjArgs pa = {xh, xl, wcat};
  const int tid = threadIdx.x, w = tid >> 6, l = tid & 63;
  const int wm = w >> 2, wn = w & 3;

  // bijective XCD swizzle: nwg=1305, q=163, r=1
  int bid = blockIdx.x;
  {
    const int xcd = bid & 7, i = bid >> 3;
    bid = ((xcd < 1) ? xcd * 164 : 164 + (xcd - 1) * 163) + i;
  }
  const int ntile = bid % 9, mtile = bid / 9;

  const int lrow8 = l >> 3;
  const int lc_sw = (l & 7) ^ lrow8;

  // per-wave staging instruction ids for each chunk (2 per wave per chunk)
  const int p0 = 2 * w, p1 = 2 * w + 1;
  const int gA0[2] = {(w < 4) ? 2 * w : 16 + 2 * (w - 4),
                      (w < 4) ? 2 * w + 1 : 17 + 2 * (w - 4)};
  const int gA1[2] = {gA0[0] + 8, gA0[1] + 8};
  const int gB0[2] = {(p0 >> 2) * 8 + (p0 & 3), (p1 >> 2) * 8 + (p1 & 3)};
  const int gB1[2] = {gB0[0] + 4, gB0[1] + 4};

  f32x4 acc[8][4];
  const f32x4 fz = {0.f, 0.f, 0.f, 0.f};
#pragma unroll
  for (int i = 0; i < 8; ++i)
#pragma unroll
    for (int j = 0; j < 4; ++j) acc[i][j] = fz;

  // ---- prologue: tile0 full (A-mh0,B-n0,A-mh1,B-n1) + tile1 (A-mh0,B-n0) ----
  {
    char* A0 = smem;            char* B0 = smem + 65536;
    char* A1 = smem + 32768;    char* B1 = smem + 98304;
    stageA(pa, 0, A0, gA0[0], mtile, lrow8, lc_sw);
    stageA(pa, 0, A0, gA0[1], mtile, lrow8, lc_sw);
    stageB(pa, 0, B0, gB0[0], ntile, lrow8, lc_sw);
    stageB(pa, 0, B0, gB0[1], ntile, lrow8, lc_sw);
    stageA(pa, 0, A0, gA1[0], mtile, lrow8, lc_sw);
    stageA(pa, 0, A0, gA1[1], mtile, lrow8, lc_sw);
    stageB(pa, 0, B0, gB1[0], ntile, lrow8, lc_sw);
    stageB(pa, 0, B0, gB1[1], ntile, lrow8, lc_sw);
    stageA(pa, 1, A1, gA0[0], mtile, lrow8, lc_sw);
    stageA(pa, 1, A1, gA0[1], mtile, lrow8, lc_sw);
    stageB(pa, 1, B1, gB0[0], ntile, lrow8, lc_sw);
    stageB(pa, 1, B1, gB0[1], ntile, lrow8, lc_sw);
  }
  asm volatile("s_waitcnt vmcnt(4)" ::: "memory");
  __builtin_amdgcn_s_barrier();

  // ---- main loop: 36 K-tiles, 4 phases each ----
  for (int t = 0; t < 36; ++t) {
    const int cur = t & 1;
    char* Ac = smem + cur * 32768;
    char* Bc = smem + 65536 + cur * 32768;
    char* An = smem + (cur ^ 1) * 32768;
    char* Bn = smem + 65536 + (cur ^ 1) * 32768;
#pragma unroll
    for (int a = 0; a < 4; ++a) {
      const int mh = a >> 1, nh = a & 1;
      // 12 ds_read_b128: 8 A-frags + 4 B-frags for this quadrant
      bf16x8 af[4][2], bf_[2][2];
#pragma unroll
      for (int mi4 = 0; mi4 < 4; ++mi4)
#pragma unroll
        for (int ks = 0; ks < 2; ++ks) {
          const int row = wm * 128 + (mh * 4 + mi4) * 16 + (l & 15);
          const int c16 = ((ks * 4) + (l >> 4)) ^ (l & 7);
          af[mi4][ks] = *reinterpret_cast<const bf16x8*>(Ac + row * 128 + c16 * 16);
        }
#pragma unroll
      for (int ni2 = 0; ni2 < 2; ++ni2)
#pragma unroll
        for (int ks = 0; ks < 2; ++ks) {
          const int row = wn * 64 + (nh * 2 + ni2) * 16 + (l & 15);
          const int c16 = ((ks * 4) + (l >> 4)) ^ (l & 7);
          bf_[ni2][ks] = *reinterpret_cast<const bf16x8*>(Bc + row * 128 + c16 * 16);
        }
      // stage (chunk-freeing ledger; see round-2 analysis)
      if (a == 0 && t + 1 < 36) {
        stageA(pa, t + 1, An, gA1[0], mtile, lrow8, lc_sw);
        stageA(pa, t + 1, An, gA1[1], mtile, lrow8, lc_sw);
      }
      if (a == 1 && t + 1 < 36) {
        stageB(pa, t + 1, Bn, gB1[0], ntile, lrow8, lc_sw);
        stageB(pa, t + 1, Bn, gB1[1], ntile, lrow8, lc_sw);
      }
      if (a == 2 && t + 2 < 36) {
        stageA(pa, t + 2, Ac, gA0[0], mtile, lrow8, lc_sw);
        stageA(pa, t + 2, Ac, gA0[1], mtile, lrow8, lc_sw);
      }
      if (a == 3 && t + 2 < 36) {
        stageB(pa, t + 2, Bc, gB0[0], ntile, lrow8, lc_sw);
        stageB(pa, t + 2, Bc, gB0[1], ntile, lrow8, lc_sw);
      }
      __builtin_amdgcn_s_barrier();
      asm volatile("s_waitcnt lgkmcnt(0)" ::: "memory");
      __builtin_amdgcn_s_setprio(1);
#pragma unroll
      for (int mi4 = 0; mi4 < 4; ++mi4)
#pragma unroll
        for (int ni2 = 0; ni2 < 2; ++ni2)
#pragma unroll
          for (int ks = 0; ks < 2; ++ks)
            acc[mh * 4 + mi4][nh * 2 + ni2] =
                MFMA16(af[mi4][ks], bf_[ni2][ks], acc[mh * 4 + mi4][nh * 2 + ni2]);
      __builtin_amdgcn_s_setprio(0);
      if (a == 3) {
        if (t < 34) asm volatile("s_waitcnt vmcnt(4)" ::: "memory");
        else        asm volatile("s_waitcnt vmcnt(0)" ::: "memory");
      }
      __builtin_amdgcn_s_barrier();
    }
  }

  // ---- epilogue: bias add, split to bf16 hi/lo, write [B,H,N,D] ----
  const int matrix = ntile / 3;  // 0=Q 1=K 2=V (256 | 768, so no tile crosses)
  const float* bias = (matrix == 0) ? bq : ((matrix == 1) ? bk : bv);
  int hh[4], dd[4];
  float bb[4];
#pragma unroll
  for (int ni = 0; ni < 4; ++ni) {
    const int n_in = (ntile % 3) * 256 + wn * 64 + ni * 16 + (l & 15);
    hh[ni] = n_in / 96;
    dd[ni] = n_in - hh[ni] * 96;
    bb[ni] = bias[n_in];
  }
#pragma unroll
  for (int mi = 0; mi < 8; ++mi) {
#pragma unroll
    for (int r = 0; r < 4; ++r) {
      const int m = mtile * 256 + wm * 128 + mi * 16 + (l >> 4) * 4 + r;
      if (m >= kM) continue;
      const int bidx = m / 577;
      const int n = m - bidx * 577;
#pragma unroll
      for (int ni = 0; ni < 4; ++ni) {
        const float val = acc[mi][ni][r] + bb[ni];
        const size_t o = ((size_t)(bidx * 8 + hh[ni]) * 577 + n) * 96 + dd[ni];
        if (matrix == 0) {
          const unsigned short hi = f2bf(val);
          Qh[o] = hi; Ql[o] = f2bf(val - bf2f(hi));
        } else if (matrix == 1) {
          const unsigned short hi = f2bf(val);
          Kh[o] = hi; Kl[o] = f2bf(val - bf2f(hi));
        } else {
          V[o] = f2bf(val);
        }
      }
    }
  }
}

// ---------------- kernel 4: V [bh][577][96] -> V^T [bh][96][640] ----------------
__global__ __launch_bounds__(256) void k_vt(const unsigned short* __restrict__ V,
                                            unsigned short* __restrict__ Vt) {
  __shared__ unsigned int Tu[32][49];
  const int nt = blockIdx.x, bh = blockIdx.y;
  const int t = threadIdx.x;
  const unsigned int* Vu = reinterpret_cast<const unsigned int*>(V);
  unsigned int* Vtu = reinterpret_cast<unsigned int*>(Vt);
  const int n0 = nt * 32;
#pragma unroll
  for (int i = 0; i < 6; ++i) {
    const int u = t + i * 256;  // < 1536
    const int ln = u / 48, cu = u - ln * 48;
    int n = n0 + ln; if (n > 576) n = 576;
    Tu[ln][cu] = Vu[(size_t)(bh * 577 + n) * 48 + cu];
  }
  __syncthreads();
#pragma unroll
  for (int i = 0; i < 6; ++i) {
    const int u = t + i * 256;
    const int d = u / 16, cu = u - d * 16;
    const unsigned int w0 = Tu[2 * cu][d >> 1];
    const unsigned int w1 = Tu[2 * cu + 1][d >> 1];
    const int sh = (d & 1) * 16;
    Vtu[(size_t)(bh * 96 + d) * 320 + nt * 16 + cu] =
        ((w0 >> sh) & 0xffffu) | (((w1 >> sh) & 0xffffu) << 16);
  }
}

// ---------------- kernel 5: fused flash attention ----------------
__global__ __launch_bounds__(256) void k_attn(
    const unsigned short* __restrict__ Qh, const unsigned short* __restrict__ Ql,
    const unsigned short* __restrict__ Kh, const unsigned short* __restrict__ Kl,
    const unsigned short* __restrict__ Vt, float* __restrict__ out) {
  __shared__ __align__(16) char sKH[16384];   // [64 kv][128 bf16 rows=256B], swizzled
  __shared__ __align__(16) char sKL[16384];
  __shared__ __align__(16) char sVT[12288];   // [96 d][64 bf16 = 128B], swizzled
  __shared__ __align__(16) char sP[4][2304];  // per-wave P: [16 q][72 bf16 = 144B]
  const int qt = blockIdx.x, bh = blockIdx.y;
  const int tid = threadIdx.x, w = tid >> 6, l = tid & 63;
  const int bb_ = bh >> 3, hh_ = bh & 7;
  const size_t hdbase = (size_t)bh * 577 * 96;

  const int qrow = qt * 64 + w * 16 + (l & 15);
  const int qn = (qrow > 576) ? 576 : qrow;

  // Q hoisted to registers: B-operand frags (hi/lo) for 3 d-ksteps
  bf16x8 fqh[3], fql[3];
#pragma unroll
  for (int ks = 0; ks < 3; ++ks) {
    const size_t off = hdbase + (size_t)qn * 96 + ks * 32 + (l >> 4) * 8;
    fqh[ks] = *reinterpret_cast<const bf16x8*>(Qh + off);
    fql[ks] = *reinterpret_cast<const bf16x8*>(Ql + off);
  }

  f32x4 accO[6];
  const f32x4 fz = {0.f, 0.f, 0.f, 0.f};
#pragma unroll
  for (int i = 0; i < 6; ++i) accO[i] = fz;
  float mrun = -1e30f, lrun = 0.f;

  for (int kt = 0; kt < 10; ++kt) {
    // ---- stage K hi/lo + V^T tiles (44 x 1KB gload_lds, 11 per wave) ----
#pragma unroll
    for (int i = 0; i < 11; ++i) {
      const int j = w * 11 + i;
      if (j < 32) {
        const int jj = j & 15;
        const int r = 4 * jj + (l >> 4);
        const int lc = (l & 15) ^ (r & 7);
        const int lc2 = (lc < 12) ? lc : 11;
        int kvn = kt * 64 + r; if (kvn > 576) kvn = 576;
        const unsigned short* src = (j < 16) ? Kh : Kl;
        char* dst = (j < 16) ? (sKH + jj * 1024) : (sKL + jj * 1024);
        gload16(src + hdbase + (size_t)kvn * 96 + lc2 * 8, dst);
      } else {
        const int j2 = j - 32;
        const int d = 8 * j2 + (l >> 3);
        const int lc = (l & 7) ^ (d & 7);
        gload16(Vt + (size_t)(bh * 96 + d) * 640 + kt * 64 + lc * 8, sVT + j2 * 1024);
      }
    }
    __syncthreads();

    // ---- S^T = K · Q^T, 3-term bf16x2 split ----
    f32x4 s_[4];
#pragma unroll
    for (int i = 0; i < 4; ++i) s_[i] = fz;
#pragma unroll
    for (int ks = 0; ks < 3; ++ks) {
#pragma unroll
      for (int af = 0; af < 4; ++af) {
        const int r = af * 16 + (l & 15);
        const int c16 = ((ks * 4) + (l >> 4)) ^ (r & 7);
        const bf16x8 kh = *reinterpret_cast<const bf16x8*>(sKH + r * 256 + c16 * 16);
        const bf16x8 kl = *reinterpret_cast<const bf16x8*>(sKL + r * 256 + c16 * 16);
        s_[af] = MFMA16(kh, fqh[ks], s_[af]);
        s_[af] = MFMA16(kh, fql[ks], s_[af]);
        s_[af] = MFMA16(kl, fqh[ks], s_[af]);
      }
    }

    if (kt == 9) {  // mask kv >= 577
#pragma unroll
      for (int af = 0; af < 4; ++af) {
        const int kv0 = 576 + af * 16 + (l >> 4) * 4;
#pragma unroll
        for (int r = 0; r < 4; ++r)
          if (kv0 + r >= 577) s_[af][r] = -1e30f;
      }
    }

    // ---- online softmax (lane holds 16 kv of its q-row; reduce over 4 lanes) ----
    float pmax = -1e30f;
#pragma unroll
    for (int af = 0; af < 4; ++af)
#pragma unroll
      for (int r = 0; r < 4; ++r) pmax = fmaxf(pmax, s_[af][r]);
    pmax = fmaxf(pmax, __shfl_xor(pmax, 16, 64));
    pmax = fmaxf(pmax, __shfl_xor(pmax, 32, 64));
    const float mnew = fmaxf(mrun, pmax);
    const float fsc = __expf(mrun - mnew);
    float psum = 0.f;
    char* pbase = sP[w] + (l & 15) * 144;
#pragma unroll
    for (int af = 0; af < 4; ++af) {
      const float p0 = __expf(s_[af][0] - mnew);
      const float p1 = __expf(s_[af][1] - mnew);
      const float p2 = __expf(s_[af][2] - mnew);
      const float p3 = __expf(s_[af][3] - mnew);
      psum += (p0 + p1) + (p2 + p3);
      const unsigned w0 = (unsigned)f2bf(p0) | ((unsigned)f2bf(p1) << 16);
      const unsigned w1 = (unsigned)f2bf(p2) | ((unsigned)f2bf(p3) << 16);
      *reinterpret_cast<unsigned*>(pbase + af * 32 + (l >> 4) * 8) = w0;
      *reinterpret_cast<unsigned*>(pbase + af * 32 + (l >> 4) * 8 + 4) = w1;
    }
    psum += __shfl_xor(psum, 16, 64);
    psum += __shfl_xor(psum, 32, 64);
    lrun = lrun * fsc + psum;
    mrun = mnew;
#pragma unroll
    for (int i = 0; i < 6; ++i)
#pragma unroll
      for (int r = 0; r < 4; ++r) accO[i][r] *= fsc;
    __syncthreads();  // cross-lane P visibility

    // ---- O^T += V^T · P^T ----
#pragma unroll
    for (int ks = 0; ks < 2; ++ks) {
      const bf16x8 pb = *reinterpret_cast<const bf16x8*>(
          sP[w] + (l & 15) * 144 + ks * 64 + (l >> 4) * 16);
#pragma unroll
      for (int df = 0; df < 6; ++df) {
        const int r = df * 16 + (l & 15);
        const int c16 = ((ks * 4) + (l >> 4)) ^ (r & 7);
        const bf16x8 va = *reinterpret_cast<const bf16x8*>(sVT + r * 128 + c16 * 16);
        accO[df] = MFMA16(va, pb, accO[df]);
      }
    }
    __syncthreads();  // reads done before next stage overwrites
  }

  // ---- epilogue: out[b][n][h*96+d] = O * scale / l ----
  if (qrow <= 576) {
    const float inv = kScale / lrun;
#pragma unroll
    for (int df = 0; df < 6; ++df) {
      float4 o;
      o.x = accO[df][0] * inv; o.y = accO[df][1] * inv;
      o.z = accO[df][2] * inv; o.w = accO[df][3] * inv;
      const size_t oo = ((size_t)bb_ * 577 + qrow) * 768 + hh_ * 96 + df * 16 + (l >> 4) * 4;
      *reinterpret_cast<float4*>(out + oo) = o;
    }
  }
}

extern "C" void kernel_launch(void* const* d_in, const int* in_sizes, int n_in,
                              void* d_out, int out_size, void* d_ws, size_t ws_size,
                              hipStream_t stream) {
  const float* x  = (const float*)d_in[0];
  const float* Wq = (const float*)d_in[1];
  const float* bq = (const float*)d_in[2];
  const float* Wk = (const float*)d_in[3];
  const float* bk = (const float*)d_in[4];
  const float* Wv = (const float*)d_in[5];
  const float* bv = (const float*)d_in[6];
  float* out = (float*)d_out;
  char* ws = (char*)d_ws;

  const size_t SZ = 56721408;  // 36928*768*2 == 512*577*96*2 bytes
  unsigned short* xh   = (unsigned short*)(ws);
  unsigned short* xl   = (unsigned short*)(ws + SZ);
  unsigned short* wcat = (unsigned short*)(ws + 2 * SZ);
  unsigned short* Qh   = (unsigned short*)(ws + 2 * SZ + 10616832);
  unsigned short* Ql   = (unsigned short*)(ws + 3 * SZ + 10616832);
  unsigned short* Kh   = (unsigned short*)(ws + 4 * SZ + 10616832);
  unsigned short* Kl   = (unsigned short*)(ws + 5 * SZ + 10616832);
  unsigned short* V    = (unsigned short*)(ws + 6 * SZ + 10616832);
  unsigned short* Vt   = (unsigned short*)(ws);  // aliases xh/xl (dead after k_proj)

  hipFuncSetAttribute((const void*)k_proj,
                      hipFuncAttributeMaxDynamicSharedMemorySize, 131072);

  k_castx<<<27696, 256, 0, stream>>>(x, xh, xl);
  k_wcat<<<20736, 256, 0, stream>>>(Wq, Wk, Wv, wcat);
  k_proj<<<dim3(1305), 512, 131072, stream>>>(xh, xl, wcat, bq, bk, bv, Qh, Ql, Kh, Kl, V);
  k_vt<<<dim3(20, 512), 256, 0, stream>>>(V, Vt);
  k_attn<<<dim3(10, 512), 256, 0, stream>>>(Qh, Ql, Kh, Kl, Vt, out);
}

// Round 3
// 825.024 us; speedup vs baseline: 1.2169x; 1.0640x over previous
//
#include <hip/hip_runtime.h>
#include <stdint.h>

typedef __bf16 bf16x8 __attribute__((ext_vector_type(8)));
typedef float  f32x4  __attribute__((ext_vector_type(4)));

#define MFMA16(a, b, c) __builtin_amdgcn_mfma_f32_16x16x32_bf16((a), (b), (c), 0, 0, 0)

static constexpr int   kBz = 64, kNn = 577, kEe = 768, kHh = 8, kDd = 96;
static constexpr int   kM  = kBz * kNn;  // 36928 tokens
static constexpr float kScale = 0.10206207261596575f;  // 96^-0.5

__device__ __forceinline__ unsigned short f2bf(float f) {
  unsigned u = __float_as_uint(f);
  u += 0x7fffu + ((u >> 16) & 1u);  // RNE
  return (unsigned short)(u >> 16);
}
__device__ __forceinline__ float bf2f(unsigned short s) {
  return __uint_as_float(((unsigned)s) << 16);
}

__device__ __forceinline__ void gload16(const void* g, void* l) {
  __builtin_amdgcn_global_load_lds(
      (const __attribute__((address_space(1))) void*)(void*)g,
      (__attribute__((address_space(3))) void*)l, 16, 0, 0);
}

// ---------------- kernel 1: split x into bf16 hi/lo ----------------
__global__ __launch_bounds__(256) void k_castx(const float* __restrict__ x,
                                               unsigned short* __restrict__ xh,
                                               unsigned short* __restrict__ xl) {
  const int i = blockIdx.x * 256 + threadIdx.x;
  if (i >= kM * kEe / 4) return;
  const float4 v = reinterpret_cast<const float4*>(x)[i];
  float f[4] = {v.x, v.y, v.z, v.w};
  ushort4 h, lo;
  unsigned short hs[4], ls[4];
#pragma unroll
  for (int j = 0; j < 4; ++j) {
    hs[j] = f2bf(f[j]);
    ls[j] = f2bf(f[j] - bf2f(hs[j]));
  }
  h.x = hs[0]; h.y = hs[1]; h.z = hs[2]; h.w = hs[3];
  lo.x = ls[0]; lo.y = ls[1]; lo.z = ls[2]; lo.w = ls[3];
  reinterpret_cast<ushort4*>(xh)[i] = h;
  reinterpret_cast<ushort4*>(xl)[i] = lo;
}

// ------- kernel 2: build W^T concat [3*768 n][2304 k] = [hi | lo | hi] -------
__global__ __launch_bounds__(256) void k_wcat(const float* __restrict__ Wq,
                                              const float* __restrict__ Wk,
                                              const float* __restrict__ Wv,
                                              unsigned short* __restrict__ wcat) {
  const int o = blockIdx.x * 256 + threadIdx.x;
  if (o >= 3 * 768 * 2304) return;
  const int gn = o / 2304, ks = o - gn * 2304;
  const int seg = ks / 768, k = ks - seg * 768;
  const int mat = gn / 768, n = gn - mat * 768;
  const float* W = (mat == 0) ? Wq : ((mat == 1) ? Wk : Wv);
  const float v = W[k * 768 + n];  // W is [k][n] row-major
  const unsigned short h = f2bf(v);
  wcat[o] = (seg == 1) ? f2bf(v - bf2f(h)) : h;
}

// ------- kernel 3: QKV projection GEMM, 256x256x64, 2-barrier reuse schedule -------
// A = [xh | xh | xl] (M=36928, K=2304), B = wcat rows (N=2304, K=2304).
// 8 waves (2M x 4N), per-wave 128x64 output. LDS: A[2][256][64] + B[2][256][64]
// bf16, XOR-swizzled. Quadrant order 00->01->11->10 with operand reuse:
// 28 ds_read_b128/wave/K-tile (vs 48 for naive quadrants). 2 barriers/K-tile.
// Early stages -> other buf {A1,B0}(t+1); late stages (post read-drain barrier)
// -> current buf {A0,B1}(t+2). vmcnt(4) at tile end drains all t+1 chunks.
struct ProjArgs {
  const unsigned short* xh; const unsigned short* xl; const unsigned short* wcat;
};

__device__ __forceinline__ void stageA(const ProjArgs& pa, int kt, char* Abuf, int g,
                                       int mtile, int lrow8, int lc_sw) {
  const unsigned short* src = (kt < 24) ? pa.xh : pa.xl;
  const int kx = (kt % 12) * 64;
  int m = mtile * 256 + 8 * g + lrow8;
  if (m > kM - 1) m = kM - 1;
  gload16(src + (size_t)m * 768 + kx + lc_sw * 8, Abuf + g * 1024);
}
__device__ __forceinline__ void stageB(const ProjArgs& pa, int kt, char* Bbuf, int g,
                                       int ntile, int lrow8, int lc_sw) {
  const int bn = ntile * 256 + 8 * g + lrow8;
  gload16(pa.wcat + (size_t)bn * 2304 + kt * 64 + lc_sw * 8, Bbuf + g * 1024);
}

__global__ __launch_bounds__(512, 2) void k_proj(
    const unsigned short* __restrict__ xh, const unsigned short* __restrict__ xl,
    const unsigned short* __restrict__ wcat,
    const float* __restrict__ bq, const float* __restrict__ bk, const float* __restrict__ bv,
    unsigned short* __restrict__ Qh, unsigned short* __restrict__ Ql,
    unsigned short* __restrict__ Kh, unsigned short* __restrict__ Kl,
    unsigned short* __restrict__ V) {
  extern __shared__ char smem[];  // 131072 B: A[2] @0/32768, B[2] @65536/98304
  const ProjArgs pa = {xh, xl, wcat};
  const int tid = threadIdx.x, w = tid >> 6, l = tid & 63;
  const int wm = w >> 2, wn = w & 3;

  // bijective XCD swizzle: nwg=1305, q=163, r=1
  int bid = blockIdx.x;
  {
    const int xcd = bid & 7, i = bid >> 3;
    bid = ((xcd < 1) ? xcd * 164 : 164 + (xcd - 1) * 163) + i;
  }
  const int ntile = bid % 9, mtile = bid / 9;

  const int lrow8 = l >> 3;
  const int lc_sw = (l & 7) ^ lrow8;

  // per-wave staging instruction ids for each chunk (2 per wave per chunk)
  const int p0 = 2 * w, p1 = 2 * w + 1;
  const int gA0[2] = {(w < 4) ? 2 * w : 16 + 2 * (w - 4),
                      (w < 4) ? 2 * w + 1 : 17 + 2 * (w - 4)};
  const int gA1[2] = {gA0[0] + 8, gA0[1] + 8};
  const int gB0[2] = {(p0 >> 2) * 8 + (p0 & 3), (p1 >> 2) * 8 + (p1 & 3)};
  const int gB1[2] = {gB0[0] + 4, gB0[1] + 4};

  f32x4 acc[8][4];
  const f32x4 fz = {0.f, 0.f, 0.f, 0.f};
#pragma unroll
  for (int i = 0; i < 8; ++i)
#pragma unroll
    for (int j = 0; j < 4; ++j) acc[i][j] = fz;

  // ---- prologue: tile0 all 4 chunks + tile1 "late-type" chunks {A0,B1} ----
  {
    char* A0b = smem;            char* B0b = smem + 65536;
    char* A1b = smem + 32768;    char* B1b = smem + 98304;
    stageA(pa, 0, A0b, gA0[0], mtile, lrow8, lc_sw);
    stageA(pa, 0, A0b, gA0[1], mtile, lrow8, lc_sw);
    stageB(pa, 0, B0b, gB0[0], ntile, lrow8, lc_sw);
    stageB(pa, 0, B0b, gB0[1], ntile, lrow8, lc_sw);
    stageA(pa, 0, A0b, gA1[0], mtile, lrow8, lc_sw);
    stageA(pa, 0, A0b, gA1[1], mtile, lrow8, lc_sw);
    stageB(pa, 0, B0b, gB1[0], ntile, lrow8, lc_sw);
    stageB(pa, 0, B0b, gB1[1], ntile, lrow8, lc_sw);
    stageA(pa, 1, A1b, gA0[0], mtile, lrow8, lc_sw);
    stageA(pa, 1, A1b, gA0[1], mtile, lrow8, lc_sw);
    stageB(pa, 1, B1b, gB1[0], ntile, lrow8, lc_sw);
    stageB(pa, 1, B1b, gB1[1], ntile, lrow8, lc_sw);
  }
  asm volatile("s_waitcnt vmcnt(4)" ::: "memory");
  __builtin_amdgcn_s_barrier();
  __builtin_amdgcn_sched_barrier(0);

  // ---- main loop: 36 K-tiles, quadrant order 00,01,11,10, 2 barriers each ----
  for (int t = 0; t < 36; ++t) {
    const int cur = t & 1;
    char* Ac = smem + cur * 32768;
    char* Bc = smem + 65536 + cur * 32768;
    char* An = smem + (cur ^ 1) * 32768;
    char* Bn = smem + 65536 + (cur ^ 1) * 32768;

    bf16x8 af[4][2], bf[2][2];

    auto readA = [&](int mh_) {
#pragma unroll
      for (int mi4 = 0; mi4 < 4; ++mi4)
#pragma unroll
        for (int ks = 0; ks < 2; ++ks) {
          const int row = wm * 128 + (mh_ * 4 + mi4) * 16 + (l & 15);
          const int c16 = ((ks * 4) + (l >> 4)) ^ (l & 7);
          af[mi4][ks] = *reinterpret_cast<const bf16x8*>(Ac + row * 128 + c16 * 16);
        }
    };
    auto readB = [&](int nh_) {
#pragma unroll
      for (int ni2 = 0; ni2 < 2; ++ni2)
#pragma unroll
        for (int ks = 0; ks < 2; ++ks) {
          const int row = wn * 64 + (nh_ * 2 + ni2) * 16 + (l & 15);
          const int c16 = ((ks * 4) + (l >> 4)) ^ (l & 7);
          bf[ni2][ks] = *reinterpret_cast<const bf16x8*>(Bc + row * 128 + c16 * 16);
        }
    };
    auto mfmaQ = [&](int mh_, int nh_) {
      __builtin_amdgcn_s_setprio(1);
#pragma unroll
      for (int mi4 = 0; mi4 < 4; ++mi4)
#pragma unroll
        for (int ni2 = 0; ni2 < 2; ++ni2)
#pragma unroll
          for (int ks = 0; ks < 2; ++ks)
            acc[mh_ * 4 + mi4][nh_ * 2 + ni2] =
                MFMA16(af[mi4][ks], bf[ni2][ks], acc[mh_ * 4 + mi4][nh_ * 2 + ni2]);
      __builtin_amdgcn_s_setprio(0);
    };

    // R1: A0 + B0, early stages {A1,B0}(t+1) -> other buffer
    readA(0);
    readB(0);
    if (t + 1 < 36) {
      stageA(pa, t + 1, An, gA1[0], mtile, lrow8, lc_sw);
      stageA(pa, t + 1, An, gA1[1], mtile, lrow8, lc_sw);
      stageB(pa, t + 1, Bn, gB0[0], ntile, lrow8, lc_sw);
      stageB(pa, t + 1, Bn, gB0[1], ntile, lrow8, lc_sw);
    }
    mfmaQ(0, 0);
    // R2: B1 (reuses bf regs; A0 kept)
    readB(1);
    mfmaQ(0, 1);
    // R3: A1 (reuses af regs; B1 kept)
    readA(1);
    // all reads of A0/B1 regions (and everything else issued so far) drained:
    asm volatile("s_waitcnt lgkmcnt(0)" ::: "memory");
    __builtin_amdgcn_s_barrier();
    __builtin_amdgcn_sched_barrier(0);
    // late stages {A0,B1}(t+2) -> current buffer (regions proven fully read)
    if (t + 2 < 36) {
      stageA(pa, t + 2, Ac, gA0[0], mtile, lrow8, lc_sw);
      stageA(pa, t + 2, Ac, gA0[1], mtile, lrow8, lc_sw);
      stageB(pa, t + 2, Bc, gB1[0], ntile, lrow8, lc_sw);
      stageB(pa, t + 2, Bc, gB1[1], ntile, lrow8, lc_sw);
    }
    mfmaQ(1, 1);
    // R4: B0 again (region overwritten only by next tile's early stages)
    readB(0);
    mfmaQ(1, 0);
    if (t < 34) asm volatile("s_waitcnt vmcnt(4)" ::: "memory");
    else        asm volatile("s_waitcnt vmcnt(0)" ::: "memory");
    __builtin_amdgcn_s_barrier();
    __builtin_amdgcn_sched_barrier(0);
  }

  // ---- epilogue: bias add, split to bf16 hi/lo, write [B,H,N,D] ----
  const int matrix = ntile / 3;  // 0=Q 1=K 2=V (256 | 768, so no tile crosses)
  const float* bias = (matrix == 0) ? bq : ((matrix == 1) ? bk : bv);
  int hh[4], dd[4];
  float bb[4];
#pragma unroll
  for (int ni = 0; ni < 4; ++ni) {
    const int n_in = (ntile % 3) * 256 + wn * 64 + ni * 16 + (l & 15);
    hh[ni] = n_in / 96;
    dd[ni] = n_in - hh[ni] * 96;
    bb[ni] = bias[n_in];
  }
#pragma unroll
  for (int mi = 0; mi < 8; ++mi) {
#pragma unroll
    for (int r = 0; r < 4; ++r) {
      const int m = mtile * 256 + wm * 128 + mi * 16 + (l >> 4) * 4 + r;
      if (m >= kM) continue;
      const int bidx = m / 577;
      const int n = m - bidx * 577;
#pragma unroll
      for (int ni = 0; ni < 4; ++ni) {
        const float val = acc[mi][ni][r] + bb[ni];
        const size_t o = ((size_t)(bidx * 8 + hh[ni]) * 577 + n) * 96 + dd[ni];
        if (matrix == 0) {
          const unsigned short hi = f2bf(val);
          Qh[o] = hi; Ql[o] = f2bf(val - bf2f(hi));
        } else if (matrix == 1) {
          const unsigned short hi = f2bf(val);
          Kh[o] = hi; Kl[o] = f2bf(val - bf2f(hi));
        } else {
          V[o] = f2bf(val);
        }
      }
    }
  }
}

// ---------------- kernel 4: V [bh][577][96] -> V^T [bh][96][640] ----------------
__global__ __launch_bounds__(256) void k_vt(const unsigned short* __restrict__ V,
                                            unsigned short* __restrict__ Vt) {
  __shared__ unsigned int Tu[32][49];
  const int nt = blockIdx.x, bh = blockIdx.y;
  const int t = threadIdx.x;
  const unsigned int* Vu = reinterpret_cast<const unsigned int*>(V);
  unsigned int* Vtu = reinterpret_cast<unsigned int*>(Vt);
  const int n0 = nt * 32;
#pragma unroll
  for (int i = 0; i < 6; ++i) {
    const int u = t + i * 256;  // < 1536
    const int ln = u / 48, cu = u - ln * 48;
    int n = n0 + ln; if (n > 576) n = 576;
    Tu[ln][cu] = Vu[(size_t)(bh * 577 + n) * 48 + cu];
  }
  __syncthreads();
#pragma unroll
  for (int i = 0; i < 6; ++i) {
    const int u = t + i * 256;
    const int d = u / 16, cu = u - d * 16;
    const unsigned int w0 = Tu[2 * cu][d >> 1];
    const unsigned int w1 = Tu[2 * cu + 1][d >> 1];
    const int sh = (d & 1) * 16;
    Vtu[(size_t)(bh * 96 + d) * 320 + nt * 16 + cu] =
        ((w0 >> sh) & 0xffffu) | (((w1 >> sh) & 0xffffu) << 16);
  }
}

// ---------------- kernel 5: fused flash attention ----------------
__global__ __launch_bounds__(256) void k_attn(
    const unsigned short* __restrict__ Qh, const unsigned short* __restrict__ Ql,
    const unsigned short* __restrict__ Kh, const unsigned short* __restrict__ Kl,
    const unsigned short* __restrict__ Vt, float* __restrict__ out) {
  __shared__ __align__(16) char sKH[16384];   // [64 kv][128 bf16 rows=256B], swizzled
  __shared__ __align__(16) char sKL[16384];
  __shared__ __align__(16) char sVT[12288];   // [96 d][64 bf16 = 128B], swizzled
  __shared__ __align__(16) char sP[4][2304];  // per-wave P: [16 q][72 bf16 = 144B]
  const int qt = blockIdx.x, bh = blockIdx.y;
  const int tid = threadIdx.x, w = tid >> 6, l = tid & 63;
  const int bb_ = bh >> 3, hh_ = bh & 7;
  const size_t hdbase = (size_t)bh * 577 * 96;

  const int qrow = qt * 64 + w * 16 + (l & 15);
  const int qn = (qrow > 576) ? 576 : qrow;

  // Q hoisted to registers: B-operand frags (hi/lo) for 3 d-ksteps
  bf16x8 fqh[3], fql[3];
#pragma unroll
  for (int ks = 0; ks < 3; ++ks) {
    const size_t off = hdbase + (size_t)qn * 96 + ks * 32 + (l >> 4) * 8;
    fqh[ks] = *reinterpret_cast<const bf16x8*>(Qh + off);
    fql[ks] = *reinterpret_cast<const bf16x8*>(Ql + off);
  }

  f32x4 accO[6];
  const f32x4 fz = {0.f, 0.f, 0.f, 0.f};
#pragma unroll
  for (int i = 0; i < 6; ++i) accO[i] = fz;
  float mrun = -1e30f, lrun = 0.f;

  for (int kt = 0; kt < 10; ++kt) {
    // ---- stage K hi/lo + V^T tiles (44 x 1KB gload_lds, 11 per wave) ----
#pragma unroll
    for (int i = 0; i < 11; ++i) {
      const int j = w * 11 + i;
      if (j < 32) {
        const int jj = j & 15;
        const int r = 4 * jj + (l >> 4);
        const int lc = (l & 15) ^ (r & 7);
        const int lc2 = (lc < 12) ? lc : 11;
        int kvn = kt * 64 + r; if (kvn > 576) kvn = 576;
        const unsigned short* src = (j < 16) ? Kh : Kl;
        char* dst = (j < 16) ? (sKH + jj * 1024) : (sKL + jj * 1024);
        gload16(src + hdbase + (size_t)kvn * 96 + lc2 * 8, dst);
      } else {
        const int j2 = j - 32;
        const int d = 8 * j2 + (l >> 3);
        const int lc = (l & 7) ^ (d & 7);
        gload16(Vt + (size_t)(bh * 96 + d) * 640 + kt * 64 + lc * 8, sVT + j2 * 1024);
      }
    }
    __syncthreads();

    // ---- S^T = K · Q^T, 3-term bf16x2 split ----
    f32x4 s_[4];
#pragma unroll
    for (int i = 0; i < 4; ++i) s_[i] = fz;
#pragma unroll
    for (int ks = 0; ks < 3; ++ks) {
#pragma unroll
      for (int af = 0; af < 4; ++af) {
        const int r = af * 16 + (l & 15);
        const int c16 = ((ks * 4) + (l >> 4)) ^ (r & 7);
        const bf16x8 kh = *reinterpret_cast<const bf16x8*>(sKH + r * 256 + c16 * 16);
        const bf16x8 kl = *reinterpret_cast<const bf16x8*>(sKL + r * 256 + c16 * 16);
        s_[af] = MFMA16(kh, fqh[ks], s_[af]);
        s_[af] = MFMA16(kh, fql[ks], s_[af]);
        s_[af] = MFMA16(kl, fqh[ks], s_[af]);
      }
    }

    if (kt == 9) {  // mask kv >= 577
#pragma unroll
      for (int af = 0; af < 4; ++af) {
        const int kv0 = 576 + af * 16 + (l >> 4) * 4;
#pragma unroll
        for (int r = 0; r < 4; ++r)
          if (kv0 + r >= 577) s_[af][r] = -1e30f;
      }
    }

    // ---- online softmax (lane holds 16 kv of its q-row; reduce over 4 lanes) ----
    float pmax = -1e30f;
#pragma unroll
    for (int af = 0; af < 4; ++af)
#pragma unroll
      for (int r = 0; r < 4; ++r) pmax = fmaxf(pmax, s_[af][r]);
    pmax = fmaxf(pmax, __shfl_xor(pmax, 16, 64));
    pmax = fmaxf(pmax, __shfl_xor(pmax, 32, 64));
    const float mnew = fmaxf(mrun, pmax);
    const float fsc = __expf(mrun - mnew);
    float psum = 0.f;
    char* pbase = sP[w] + (l & 15) * 144;
#pragma unroll
    for (int af = 0; af < 4; ++af) {
      const float p0 = __expf(s_[af][0] - mnew);
      const float p1 = __expf(s_[af][1] - mnew);
      const float p2 = __expf(s_[af][2] - mnew);
      const float p3 = __expf(s_[af][3] - mnew);
      psum += (p0 + p1) + (p2 + p3);
      const unsigned w0 = (unsigned)f2bf(p0) | ((unsigned)f2bf(p1) << 16);
      const unsigned w1 = (unsigned)f2bf(p2) | ((unsigned)f2bf(p3) << 16);
      *reinterpret_cast<unsigned*>(pbase + af * 32 + (l >> 4) * 8) = w0;
      *reinterpret_cast<unsigned*>(pbase + af * 32 + (l >> 4) * 8 + 4) = w1;
    }
    psum += __shfl_xor(psum, 16, 64);
    psum += __shfl_xor(psum, 32, 64);
    lrun = lrun * fsc + psum;
    mrun = mnew;
#pragma unroll
    for (int i = 0; i < 6; ++i)
#pragma unroll
      for (int r = 0; r < 4; ++r) accO[i][r] *= fsc;
    __syncthreads();  // cross-lane P visibility

    // ---- O^T += V^T · P^T ----
#pragma unroll
    for (int ks = 0; ks < 2; ++ks) {
      const bf16x8 pb = *reinterpret_cast<const bf16x8*>(
          sP[w] + (l & 15) * 144 + ks * 64 + (l >> 4) * 16);
#pragma unroll
      for (int df = 0; df < 6; ++df) {
        const int r = df * 16 + (l & 15);
        const int c16 = ((ks * 4) + (l >> 4)) ^ (r & 7);
        const bf16x8 va = *reinterpret_cast<const bf16x8*>(sVT + r * 128 + c16 * 16);
        accO[df] = MFMA16(va, pb, accO[df]);
      }
    }
    __syncthreads();  // reads done before next stage overwrites
  }

  // ---- epilogue: out[b][n][h*96+d] = O * scale / l ----
  if (qrow <= 576) {
    const float inv = kScale / lrun;
#pragma unroll
    for (int df = 0; df < 6; ++df) {
      float4 o;
      o.x = accO[df][0] * inv; o.y = accO[df][1] * inv;
      o.z = accO[df][2] * inv; o.w = accO[df][3] * inv;
      const size_t oo = ((size_t)bb_ * 577 + qrow) * 768 + hh_ * 96 + df * 16 + (l >> 4) * 4;
      *reinterpret_cast<float4*>(out + oo) = o;
    }
  }
}

extern "C" void kernel_launch(void* const* d_in, const int* in_sizes, int n_in,
                              void* d_out, int out_size, void* d_ws, size_t ws_size,
                              hipStream_t stream) {
  const float* x  = (const float*)d_in[0];
  const float* Wq = (const float*)d_in[1];
  const float* bq = (const float*)d_in[2];
  const float* Wk = (const float*)d_in[3];
  const float* bk = (const float*)d_in[4];
  const float* Wv = (const float*)d_in[5];
  const float* bv = (const float*)d_in[6];
  float* out = (float*)d_out;
  char* ws = (char*)d_ws;

  const size_t SZ = 56721408;  // 36928*768*2 == 512*577*96*2 bytes
  unsigned short* xh   = (unsigned short*)(ws);
  unsigned short* xl   = (unsigned short*)(ws + SZ);
  unsigned short* wcat = (unsigned short*)(ws + 2 * SZ);
  unsigned short* Qh   = (unsigned short*)(ws + 2 * SZ + 10616832);
  unsigned short* Ql   = (unsigned short*)(ws + 3 * SZ + 10616832);
  unsigned short* Kh   = (unsigned short*)(ws + 4 * SZ + 10616832);
  unsigned short* Kl   = (unsigned short*)(ws + 5 * SZ + 10616832);
  unsigned short* V    = (unsigned short*)(ws + 6 * SZ + 10616832);
  unsigned short* Vt   = (unsigned short*)(ws);  // aliases xh/xl (dead after k_proj)

  hipFuncSetAttribute((const void*)k_proj,
                      hipFuncAttributeMaxDynamicSharedMemorySize, 131072);

  k_castx<<<27696, 256, 0, stream>>>(x, xh, xl);
  k_wcat<<<20736, 256, 0, stream>>>(Wq, Wk, Wv, wcat);
  k_proj<<<dim3(1305), 512, 131072, stream>>>(xh, xl, wcat, bq, bk, bv, Qh, Ql, Kh, Kl, V);
  k_vt<<<dim3(20, 512), 256, 0, stream>>>(V, Vt);
  k_attn<<<dim3(10, 512), 256, 0, stream>>>(Qh, Ql, Kh, Kl, Vt, out);
}